// Round 1
// baseline (783.119 us; speedup 1.0000x reference)
//
#include <hip/hip_runtime.h>
#include <hip/hip_bf16.h>

#define NEG_SLOPE 0.2f
#define EPSF 1e-16f

// -------------------- GEMM1: h1[N,64] = x[N,512] @ W1[512,64] --------------------
__global__ __launch_bounds__(256) void gemm1_kernel(const float* __restrict__ x,
                                                    const float* __restrict__ W,
                                                    float* __restrict__ h1, int N) {
  __shared__ __align__(16) float xs[32][68];  // xs[k][r]  (transposed x tile)
  __shared__ __align__(16) float wsm[32][68]; // wsm[k][c]
  const int tid = threadIdx.x;
  const int row0 = blockIdx.x * 64;
  const int tx = tid & 15, ty = tid >> 4;   // ty: 0..15 (rows), tx: 0..15 (cols)
  float acc[4][4] = {};
  const int li = tid >> 3;        // 0..31
  const int lj = (tid & 7) * 4;   // 0,4,...,28

  for (int k0 = 0; k0 < 512; k0 += 32) {
    // stage x tile (64 rows x 32 k), transposed into xs[k][r]
    {
      int r = row0 + li;
      float4 v = make_float4(0.f, 0.f, 0.f, 0.f);
      if (r < N) v = *(const float4*)(x + (size_t)r * 512 + k0 + lj);
      xs[lj + 0][li] = v.x; xs[lj + 1][li] = v.y; xs[lj + 2][li] = v.z; xs[lj + 3][li] = v.w;
      int r2 = r + 32;
      float4 v2 = make_float4(0.f, 0.f, 0.f, 0.f);
      if (r2 < N) v2 = *(const float4*)(x + (size_t)r2 * 512 + k0 + lj);
      xs[lj + 0][li + 32] = v2.x; xs[lj + 1][li + 32] = v2.y; xs[lj + 2][li + 32] = v2.z; xs[lj + 3][li + 32] = v2.w;
    }
    // stage W tile (32 k x 64 c)
#pragma unroll
    for (int l = 0; l < 2; ++l) {
      int idx = tid + l * 256;
      int kk = idx >> 4, c4 = (idx & 15) * 4;
      float4 w = *(const float4*)(W + (size_t)(k0 + kk) * 64 + c4);
      wsm[kk][c4 + 0] = w.x; wsm[kk][c4 + 1] = w.y; wsm[kk][c4 + 2] = w.z; wsm[kk][c4 + 3] = w.w;
    }
    __syncthreads();
#pragma unroll
    for (int k = 0; k < 32; ++k) {
      float4 a = *(const float4*)&xs[k][ty * 4];
      float4 b = *(const float4*)&wsm[k][tx * 4];
      float av[4] = {a.x, a.y, a.z, a.w};
      float bv[4] = {b.x, b.y, b.z, b.w};
#pragma unroll
      for (int i = 0; i < 4; ++i)
#pragma unroll
        for (int j = 0; j < 4; ++j)
          acc[i][j] = fmaf(av[i], bv[j], acc[i][j]);
    }
    __syncthreads();
  }
#pragma unroll
  for (int i = 0; i < 4; ++i) {
    int r = row0 + ty * 4 + i;
    if (r < N) {
      float4 o = make_float4(acc[i][0], acc[i][1], acc[i][2], acc[i][3]);
      *(float4*)(h1 + (size_t)r * 64 + tx * 4) = o;
    }
  }
}

// -------------------- per-node attention scalars, layer 1 --------------------
__global__ __launch_bounds__(256) void att1_kernel(const float* __restrict__ h1,
                                                   const float* __restrict__ atts,
                                                   const float* __restrict__ attd,
                                                   float* __restrict__ a1s, float* __restrict__ a1d, int N) {
  int gid = blockIdx.x * 256 + threadIdx.x;
  if (gid >= N * 8) return;
  int n = gid >> 3, h = gid & 7;
  const float* hp = h1 + (size_t)n * 64 + h * 8;
  float s = 0.f, d = 0.f;
#pragma unroll
  for (int c = 0; c < 8; ++c) {
    s = fmaf(hp[c], atts[h * 8 + c], s);
    d = fmaf(hp[c], attd[h * 8 + c], d);
  }
  a1s[gid] = s;
  a1d[gid] = d;
}

// -------------------- edge pass, layer 1 (thread per (edge, channel64)) --------------------
__global__ __launch_bounds__(256) void edge1_kernel(const int* __restrict__ ei, int E, int ET,
                                                    const float* __restrict__ a1s, const float* __restrict__ a1d,
                                                    const float* __restrict__ h1,
                                                    float* __restrict__ acc1, float* __restrict__ s1) {
  long long gid = (long long)blockIdx.x * 256 + threadIdx.x;
  long long e = gid >> 6;
  if (e >= ET) return;
  int j = (int)(gid & 63), h = j >> 3;
  int s, d;
  if (e < E) { s = ei[e]; d = ei[E + e]; }
  else       { s = d = (int)(e - E); }
  float al = a1s[s * 8 + h] + a1d[d * 8 + h];
  al = (al > 0.f) ? al : NEG_SLOPE * al;
  float w = __expf(al);
  unsafeAtomicAdd(&acc1[(size_t)d * 64 + j], w * h1[(size_t)s * 64 + j]);
  if ((j & 7) == 0) unsafeAtomicAdd(&s1[(size_t)d * 8 + h], w);
}

// -------------------- normalize + bias + ELU (acc1 -> h2 in place) --------------------
__global__ __launch_bounds__(256) void norm_elu_kernel(float* __restrict__ acc1, const float* __restrict__ s1,
                                                       const float* __restrict__ bias1, int N) {
  int gid = blockIdx.x * 256 + threadIdx.x;
  if (gid >= N * 64) return;
  int n = gid >> 6, h = (gid >> 3) & 7;
  float v = acc1[gid] / (s1[n * 8 + h] + EPSF) + bias1[gid & 63];
  acc1[gid] = (v > 0.f) ? v : expm1f(v);
}

// -------------------- layer2 projection g = h2 @ W2 + attention scalars --------------------
__global__ __launch_bounds__(256) void l2_proj_kernel(const float* __restrict__ h2, const float* __restrict__ W2,
                                                      const float* __restrict__ atts, const float* __restrict__ attd,
                                                      float* __restrict__ g, float* __restrict__ a2s,
                                                      float* __restrict__ a2d, int N) {
  __shared__ float w[1024];
  int tid = threadIdx.x;
  for (int i = tid; i < 1024; i += 256) w[i] = W2[i];
  __syncthreads();
  int gid = blockIdx.x * 256 + tid;
  int n = gid >> 4, c = gid & 15;
  if (n >= N) return;
  const float* hr = h2 + (size_t)n * 64;
  float acc = 0.f;
#pragma unroll
  for (int k = 0; k < 64; ++k) acc = fmaf(hr[k], w[k * 16 + c], acc);
  g[(size_t)n * 16 + c] = acc;
  float ps = acc * atts[c], pd = acc * attd[c];
#pragma unroll
  for (int m = 1; m < 16; m <<= 1) { ps += __shfl_xor(ps, m); pd += __shfl_xor(pd, m); }
  if (c == 0) { a2s[n] = ps; a2d[n] = pd; }
}

// -------------------- edge pass, layer 2 (thread per (edge, channel16)) --------------------
__global__ __launch_bounds__(256) void edge2_kernel(const int* __restrict__ ei, int E, int ET,
                                                    const float* __restrict__ a2s, const float* __restrict__ a2d,
                                                    const float* __restrict__ g,
                                                    float* __restrict__ acc2, float* __restrict__ s2) {
  long long gid = (long long)blockIdx.x * 256 + threadIdx.x;
  long long e = gid >> 4;
  if (e >= ET) return;
  int c = (int)(gid & 15);
  int s, d;
  if (e < E) { s = ei[e]; d = ei[E + e]; }
  else       { s = d = (int)(e - E); }
  float al = a2s[s] + a2d[d];
  al = (al > 0.f) ? al : NEG_SLOPE * al;
  float w = __expf(al);
  unsafeAtomicAdd(&acc2[(size_t)d * 16 + c], w * g[(size_t)s * 16 + c]);
  if (c == 0) unsafeAtomicAdd(&s2[d], w);
}

// -------------------- final: normalize emb (in place) + softmax --------------------
__global__ __launch_bounds__(256) void final_kernel(float* __restrict__ emb, const float* __restrict__ s2,
                                                    const float* __restrict__ bias2,
                                                    float* __restrict__ out_sm, int N) {
  int gid = blockIdx.x * 256 + threadIdx.x;
  int n = gid >> 4, c = gid & 15;
  if (n >= N) return;
  float v = emb[(size_t)n * 16 + c] / (s2[n] + EPSF) + bias2[c];
  emb[(size_t)n * 16 + c] = v;
  float m = v;
#pragma unroll
  for (int k = 1; k < 16; k <<= 1) m = fmaxf(m, __shfl_xor(m, k));
  float e = __expf(v - m);
  float ssum = e;
#pragma unroll
  for (int k = 1; k < 16; k <<= 1) ssum += __shfl_xor(ssum, k);
  out_sm[(size_t)n * 16 + c] = e / ssum;
}

extern "C" void kernel_launch(void* const* d_in, const int* in_sizes, int n_in,
                              void* d_out, int out_size, void* d_ws, size_t ws_size,
                              hipStream_t stream) {
  const float* x     = (const float*)d_in[0];
  const int*   ei    = (const int*)d_in[1];
  const float* W1    = (const float*)d_in[2];
  const float* atts1 = (const float*)d_in[3];
  const float* attd1 = (const float*)d_in[4];
  const float* bias1 = (const float*)d_in[5];
  const float* W2    = (const float*)d_in[6];
  const float* atts2 = (const float*)d_in[7];
  const float* attd2 = (const float*)d_in[8];
  const float* bias2 = (const float*)d_in[9];

  const int N = in_sizes[0] / 512;
  const int E = in_sizes[1] / 2;
  const int ET = E + N;

  float* ws  = (float*)d_ws;
  float* h1  = ws;                      // N*64
  float* a1s = h1  + (size_t)N * 64;    // N*8
  float* a1d = a1s + (size_t)N * 8;     // N*8
  float* s1  = a1d + (size_t)N * 8;     // N*8
  float* acc1= s1  + (size_t)N * 8;     // N*64  (becomes h2 in place)
  float* g   = acc1+ (size_t)N * 64;    // N*16
  float* a2s = g   + (size_t)N * 16;    // N
  float* a2d = a2s + N;                 // N
  float* s2  = a2d + N;                 // N

  float* out_sm = (float*)d_out;                 // softmax output [N,16]
  float* emb    = out_sm + (size_t)N * 16;       // node_embeddings [N,16] (used as acc2)

  hipMemsetAsync(s1,   0, (size_t)N * 8 * sizeof(float), stream);
  hipMemsetAsync(acc1, 0, (size_t)N * 64 * sizeof(float), stream);
  hipMemsetAsync(s2,   0, (size_t)N * sizeof(float), stream);
  hipMemsetAsync(emb,  0, (size_t)N * 16 * sizeof(float), stream);

  gemm1_kernel<<<(N + 63) / 64, 256, 0, stream>>>(x, W1, h1, N);
  att1_kernel<<<(N * 8 + 255) / 256, 256, 0, stream>>>(h1, atts1, attd1, a1s, a1d, N);
  edge1_kernel<<<(int)(((long long)ET * 64 + 255) / 256), 256, 0, stream>>>(ei, E, ET, a1s, a1d, h1, acc1, s1);
  norm_elu_kernel<<<(N * 64 + 255) / 256, 256, 0, stream>>>(acc1, s1, bias1, N);
  l2_proj_kernel<<<(N * 16 + 255) / 256, 256, 0, stream>>>(acc1, W2, atts2, attd2, g, a2s, a2d, N);
  edge2_kernel<<<(int)(((long long)ET * 16 + 255) / 256), 256, 0, stream>>>(ei, E, ET, a2s, a2d, g, emb, s2);
  final_kernel<<<(N * 16 + 255) / 256, 256, 0, stream>>>(emb, s2, bias2, out_sm, N);
}

// Round 2
// 481.831 us; speedup vs baseline: 1.6253x; 1.6253x over previous
//
#include <hip/hip_runtime.h>
#include <hip/hip_bf16.h>

#define NEG_SLOPE 0.2f
#define EPSF 1e-16f

// -------------------- GEMM1: h1[N,64] = x[N,512] @ W1[512,64] --------------------
__global__ __launch_bounds__(256) void gemm1_kernel(const float* __restrict__ x,
                                                    const float* __restrict__ W,
                                                    float* __restrict__ h1, int N) {
  __shared__ __align__(16) float xs[32][68];  // xs[k][r]  (transposed x tile)
  __shared__ __align__(16) float wsm[32][68]; // wsm[k][c]
  const int tid = threadIdx.x;
  const int row0 = blockIdx.x * 64;
  const int tx = tid & 15, ty = tid >> 4;
  float acc[4][4] = {};
  const int li = tid >> 3;
  const int lj = (tid & 7) * 4;

  for (int k0 = 0; k0 < 512; k0 += 32) {
    {
      int r = row0 + li;
      float4 v = make_float4(0.f, 0.f, 0.f, 0.f);
      if (r < N) v = *(const float4*)(x + (size_t)r * 512 + k0 + lj);
      xs[lj + 0][li] = v.x; xs[lj + 1][li] = v.y; xs[lj + 2][li] = v.z; xs[lj + 3][li] = v.w;
      int r2 = r + 32;
      float4 v2 = make_float4(0.f, 0.f, 0.f, 0.f);
      if (r2 < N) v2 = *(const float4*)(x + (size_t)r2 * 512 + k0 + lj);
      xs[lj + 0][li + 32] = v2.x; xs[lj + 1][li + 32] = v2.y; xs[lj + 2][li + 32] = v2.z; xs[lj + 3][li + 32] = v2.w;
    }
#pragma unroll
    for (int l = 0; l < 2; ++l) {
      int idx = tid + l * 256;
      int kk = idx >> 4, c4 = (idx & 15) * 4;
      float4 w = *(const float4*)(W + (size_t)(k0 + kk) * 64 + c4);
      wsm[kk][c4 + 0] = w.x; wsm[kk][c4 + 1] = w.y; wsm[kk][c4 + 2] = w.z; wsm[kk][c4 + 3] = w.w;
    }
    __syncthreads();
#pragma unroll
    for (int k = 0; k < 32; ++k) {
      float4 a = *(const float4*)&xs[k][ty * 4];
      float4 b = *(const float4*)&wsm[k][tx * 4];
      float av[4] = {a.x, a.y, a.z, a.w};
      float bv[4] = {b.x, b.y, b.z, b.w};
#pragma unroll
      for (int i = 0; i < 4; ++i)
#pragma unroll
        for (int j = 0; j < 4; ++j)
          acc[i][j] = fmaf(av[i], bv[j], acc[i][j]);
    }
    __syncthreads();
  }
#pragma unroll
  for (int i = 0; i < 4; ++i) {
    int r = row0 + ty * 4 + i;
    if (r < N) {
      float4 o = make_float4(acc[i][0], acc[i][1], acc[i][2], acc[i][3]);
      *(float4*)(h1 + (size_t)r * 64 + tx * 4) = o;
    }
  }
}

// -------------------- per-node attention scalars, layer 1 --------------------
__global__ __launch_bounds__(256) void att1_kernel(const float* __restrict__ h1,
                                                   const float* __restrict__ atts,
                                                   const float* __restrict__ attd,
                                                   float* __restrict__ a1s, float* __restrict__ a1d, int N) {
  int gid = blockIdx.x * 256 + threadIdx.x;
  if (gid >= N * 8) return;
  int n = gid >> 3, h = gid & 7;
  const float* hp = h1 + (size_t)n * 64 + h * 8;
  float s = 0.f, d = 0.f;
#pragma unroll
  for (int c = 0; c < 8; ++c) {
    s = fmaf(hp[c], atts[h * 8 + c], s);
    d = fmaf(hp[c], attd[h * 8 + c], d);
  }
  a1s[gid] = s;
  a1d[gid] = d;
}

// -------------------- CSR build --------------------
__global__ __launch_bounds__(256) void init_deg_kernel(int* __restrict__ deg, int N) {
  int i = blockIdx.x * 256 + threadIdx.x;
  if (i < N) deg[i] = 1;  // self-loop
}

__global__ __launch_bounds__(256) void count_kernel(const int* __restrict__ ei, int E, int* __restrict__ deg) {
  int e = blockIdx.x * 256 + threadIdx.x;
  if (e < E) atomicAdd(&deg[ei[E + e]], 1);
}

// exclusive scan, stage 1: per-1024-block scan (in place deg->excl ok), block sums out
__global__ __launch_bounds__(256) void scan1_kernel(int* __restrict__ data, int* __restrict__ blocksum, int N) {
  __shared__ int wave_tot[4];
  int t = threadIdx.x;
  int base = blockIdx.x * 1024;
  int v[4];
  int sum = 0;
#pragma unroll
  for (int i = 0; i < 4; ++i) {
    int idx = base + t * 4 + i;
    v[i] = sum;
    int d = (idx < N) ? data[idx] : 0;
    sum += d;
  }
  int lane = t & 63, wv = t >> 6;
  int x = sum;
#pragma unroll
  for (int ofs = 1; ofs < 64; ofs <<= 1) {
    int y = __shfl_up(x, ofs);
    if (lane >= ofs) x += y;
  }
  if (lane == 63) wave_tot[wv] = x;
  __syncthreads();
  int wofs = 0;
  for (int w = 0; w < wv; ++w) wofs += wave_tot[w];
  int excl_thread = wofs + x - sum;
#pragma unroll
  for (int i = 0; i < 4; ++i) {
    int idx = base + t * 4 + i;
    if (idx < N) data[idx] = excl_thread + v[i];
  }
  if (t == 255) blocksum[blockIdx.x] = wofs + x;
}

// stage 2: exclusive scan of block sums (single block; nb <= 256)
__global__ __launch_bounds__(256) void scan2_kernel(int* __restrict__ blocksum, int nb) {
  __shared__ int sm[256];
  int t = threadIdx.x;
  int x = (t < nb) ? blocksum[t] : 0;
  sm[t] = x;
  __syncthreads();
  for (int ofs = 1; ofs < 256; ofs <<= 1) {
    int y = (t >= ofs) ? sm[t - ofs] : 0;
    __syncthreads();
    sm[t] += y;
    __syncthreads();
  }
  if (t < nb) blocksum[t] = sm[t] - x;  // exclusive
}

// stage 3: add block offsets -> rowptr, init cursor
__global__ __launch_bounds__(256) void scan3_kernel(const int* __restrict__ excl, const int* __restrict__ blocksum,
                                                    int* __restrict__ rowptr, int* __restrict__ cursor,
                                                    int N, int ET) {
  int idx = blockIdx.x * 256 + threadIdx.x;
  if (idx < N) {
    int r = excl[idx] + blocksum[idx >> 10];
    rowptr[idx] = r;
    cursor[idx] = r;
  }
  if (idx == N) rowptr[N] = ET;
}

__global__ __launch_bounds__(256) void scatter_kernel(const int* __restrict__ ei, int E, int ET,
                                                      int* __restrict__ cursor, int* __restrict__ esrc) {
  int e = blockIdx.x * 256 + threadIdx.x;
  if (e >= ET) return;
  int s, d;
  if (e < E) { s = ei[e]; d = ei[E + e]; }
  else       { s = d = e - E; }
  int pos = atomicAdd(&cursor[d], 1);
  esrc[pos] = s;
}

// -------------------- layer-1 aggregation: wave per dst node, lane = channel --------------------
__global__ __launch_bounds__(256) void agg1_kernel(const int* __restrict__ rowptr, const int* __restrict__ esrc,
                                                   const float* __restrict__ a1s, const float* __restrict__ a1d,
                                                   const float* __restrict__ h1, const float* __restrict__ bias1,
                                                   float* __restrict__ h2, int N) {
  int wid = (blockIdx.x * 256 + threadIdx.x) >> 6;
  int lane = threadIdx.x & 63;
  if (wid >= N) return;
  int n = wid;
  int h = lane >> 3;
  float ad = a1d[n * 8 + h];
  int beg = rowptr[n], end = rowptr[n + 1];
  float acc = 0.f, wsum = 0.f;
  int k = beg;
  for (; k + 1 < end; k += 2) {
    int s0 = esrc[k], s1 = esrc[k + 1];
    float al0 = a1s[s0 * 8 + h] + ad;
    float al1 = a1s[s1 * 8 + h] + ad;
    float g0 = h1[(size_t)s0 * 64 + lane];
    float g1 = h1[(size_t)s1 * 64 + lane];
    al0 = (al0 > 0.f) ? al0 : NEG_SLOPE * al0;
    al1 = (al1 > 0.f) ? al1 : NEG_SLOPE * al1;
    float w0 = __expf(al0), w1 = __expf(al1);
    acc = fmaf(w0, g0, acc);
    acc = fmaf(w1, g1, acc);
    wsum += w0 + w1;
  }
  if (k < end) {
    int s0 = esrc[k];
    float al0 = a1s[s0 * 8 + h] + ad;
    float g0 = h1[(size_t)s0 * 64 + lane];
    al0 = (al0 > 0.f) ? al0 : NEG_SLOPE * al0;
    float w0 = __expf(al0);
    acc = fmaf(w0, g0, acc);
    wsum += w0;
  }
  float v = acc / (wsum + EPSF) + bias1[lane];
  h2[(size_t)n * 64 + lane] = (v > 0.f) ? v : expm1f(v);
}

// -------------------- layer2 projection g = h2 @ W2 + attention scalars --------------------
__global__ __launch_bounds__(256) void l2_proj_kernel(const float* __restrict__ h2, const float* __restrict__ W2,
                                                      const float* __restrict__ atts, const float* __restrict__ attd,
                                                      float* __restrict__ g, float* __restrict__ a2s,
                                                      float* __restrict__ a2d, int N) {
  __shared__ float w[1024];
  int tid = threadIdx.x;
  for (int i = tid; i < 1024; i += 256) w[i] = W2[i];
  __syncthreads();
  int gid = blockIdx.x * 256 + tid;
  int n = gid >> 4, c = gid & 15;
  if (n >= N) return;
  const float* hr = h2 + (size_t)n * 64;
  float acc = 0.f;
#pragma unroll
  for (int k = 0; k < 64; ++k) acc = fmaf(hr[k], w[k * 16 + c], acc);
  g[(size_t)n * 16 + c] = acc;
  float ps = acc * atts[c], pd = acc * attd[c];
#pragma unroll
  for (int m = 1; m < 16; m <<= 1) { ps += __shfl_xor(ps, m); pd += __shfl_xor(pd, m); }
  if (c == 0) { a2s[n] = ps; a2d[n] = pd; }
}

// -------------------- layer-2 aggregation + bias + softmax (fused final) --------------------
__global__ __launch_bounds__(256) void agg2_kernel(const int* __restrict__ rowptr, const int* __restrict__ esrc,
                                                   const float* __restrict__ a2s, const float* __restrict__ a2d,
                                                   const float* __restrict__ g, const float* __restrict__ bias2,
                                                   float* __restrict__ out_sm, float* __restrict__ emb, int N) {
  int wid = (blockIdx.x * 256 + threadIdx.x) >> 6;
  int lane = threadIdx.x & 63;
  if (wid >= N) return;
  int n = wid;
  int c = lane & 15, sub = lane >> 4;
  float ad = a2d[n];
  int beg = rowptr[n], end = rowptr[n + 1];
  float acc = 0.f, wsum = 0.f;
  for (int k = beg + sub; k < end; k += 4) {
    int s = esrc[k];
    float al = a2s[s] + ad;
    al = (al > 0.f) ? al : NEG_SLOPE * al;
    float w = __expf(al);
    acc = fmaf(w, g[(size_t)s * 16 + c], acc);
    wsum += w;
  }
  acc += __shfl_xor(acc, 16); acc += __shfl_xor(acc, 32);
  wsum += __shfl_xor(wsum, 16); wsum += __shfl_xor(wsum, 32);
  float v = acc / (wsum + EPSF) + bias2[c];
  float m = v;
#pragma unroll
  for (int k2 = 1; k2 < 16; k2 <<= 1) m = fmaxf(m, __shfl_xor(m, k2));
  float e = __expf(v - m);
  float ssum = e;
#pragma unroll
  for (int k2 = 1; k2 < 16; k2 <<= 1) ssum += __shfl_xor(ssum, k2);
  if (sub == 0) {
    emb[(size_t)n * 16 + c] = v;
    out_sm[(size_t)n * 16 + c] = e / ssum;
  }
}

extern "C" void kernel_launch(void* const* d_in, const int* in_sizes, int n_in,
                              void* d_out, int out_size, void* d_ws, size_t ws_size,
                              hipStream_t stream) {
  const float* x     = (const float*)d_in[0];
  const int*   ei    = (const int*)d_in[1];
  const float* W1    = (const float*)d_in[2];
  const float* atts1 = (const float*)d_in[3];
  const float* attd1 = (const float*)d_in[4];
  const float* bias1 = (const float*)d_in[5];
  const float* W2    = (const float*)d_in[6];
  const float* atts2 = (const float*)d_in[7];
  const float* attd2 = (const float*)d_in[8];
  const float* bias2 = (const float*)d_in[9];

  const int N = in_sizes[0] / 512;
  const int E = in_sizes[1] / 2;
  const int ET = E + N;

  // workspace layout (4-byte elems). g/a2s/a2d alias the h1 region (dead by then).
  float* ws   = (float*)d_ws;
  float* h1   = ws;                       // N*64  (later reused: g N*16, a2s N, a2d N)
  float* a1s  = h1  + (size_t)N * 64;     // N*8
  float* a1d  = a1s + (size_t)N * 8;      // N*8
  float* h2   = a1d + (size_t)N * 8;      // N*64
  int*   deg  = (int*)(h2 + (size_t)N * 64); // N (in-place becomes excl-scan)
  int*   rowptr = deg + N;                // N+1
  int*   cursor = rowptr + N + 1;         // N
  int*   blocksum = cursor + N;           // 256
  int*   esrc = blocksum + 256;           // ET

  float* g   = h1;                        // N*16 (aliases h1)
  float* a2s = h1 + (size_t)N * 16;       // N
  float* a2d = a2s + N;                   // N

  float* out_sm = (float*)d_out;            // softmax output [N,16]
  float* emb    = out_sm + (size_t)N * 16;  // node_embeddings [N,16]

  const int nb = (N + 1023) / 1024;  // scan blocks (<=256 for N<=262144)

  // CSR build
  init_deg_kernel<<<(N + 255) / 256, 256, 0, stream>>>(deg, N);
  count_kernel<<<(E + 255) / 256, 256, 0, stream>>>(ei, E, deg);
  scan1_kernel<<<nb, 256, 0, stream>>>(deg, blocksum, N);
  scan2_kernel<<<1, 256, 0, stream>>>(blocksum, nb);
  scan3_kernel<<<(N + 256) / 256, 256, 0, stream>>>(deg, blocksum, rowptr, cursor, N, ET);
  scatter_kernel<<<(ET + 255) / 256, 256, 0, stream>>>(ei, E, ET, cursor, esrc);

  // layer 1
  gemm1_kernel<<<(N + 63) / 64, 256, 0, stream>>>(x, W1, h1, N);
  att1_kernel<<<(N * 8 + 255) / 256, 256, 0, stream>>>(h1, atts1, attd1, a1s, a1d, N);
  agg1_kernel<<<(N + 3) / 4, 256, 0, stream>>>(rowptr, esrc, a1s, a1d, h1, bias1, h2, N);

  // layer 2
  l2_proj_kernel<<<(N * 16 + 255) / 256, 256, 0, stream>>>(h2, W2, atts2, attd2, g, a2s, a2d, N);
  agg2_kernel<<<(N + 3) / 4, 256, 0, stream>>>(rowptr, esrc, a2s, a2d, g, bias2, out_sm, emb, N);
}

// Round 3
// 438.920 us; speedup vs baseline: 1.7842x; 1.0978x over previous
//
#include <hip/hip_runtime.h>
#include <hip/hip_bf16.h>

#define NEG_SLOPE 0.2f
#define EPSF 1e-16f

// -------------------- GEMM1 + fused att1: h1 = x @ W1; a1s/a1d per (node, head) --------------------
__global__ __launch_bounds__(256) void gemm1_kernel(const float* __restrict__ x,
                                                    const float* __restrict__ W,
                                                    const float* __restrict__ atts,
                                                    const float* __restrict__ attd,
                                                    float* __restrict__ h1,
                                                    float* __restrict__ a1s,
                                                    float* __restrict__ a1d, int N) {
  __shared__ __align__(16) float xs[32][68];  // xs[k][r]  (transposed x tile)
  __shared__ __align__(16) float wsm[32][68]; // wsm[k][c]
  const int tid = threadIdx.x;
  const int row0 = blockIdx.x * 64;
  const int tx = tid & 15, ty = tid >> 4;
  float acc[4][4] = {};
  const int li = tid >> 3;
  const int lj = (tid & 7) * 4;

  for (int k0 = 0; k0 < 512; k0 += 32) {
    {
      int r = row0 + li;
      float4 v = make_float4(0.f, 0.f, 0.f, 0.f);
      if (r < N) v = *(const float4*)(x + (size_t)r * 512 + k0 + lj);
      xs[lj + 0][li] = v.x; xs[lj + 1][li] = v.y; xs[lj + 2][li] = v.z; xs[lj + 3][li] = v.w;
      int r2 = r + 32;
      float4 v2 = make_float4(0.f, 0.f, 0.f, 0.f);
      if (r2 < N) v2 = *(const float4*)(x + (size_t)r2 * 512 + k0 + lj);
      xs[lj + 0][li + 32] = v2.x; xs[lj + 1][li + 32] = v2.y; xs[lj + 2][li + 32] = v2.z; xs[lj + 3][li + 32] = v2.w;
    }
#pragma unroll
    for (int l = 0; l < 2; ++l) {
      int idx = tid + l * 256;
      int kk = idx >> 4, c4 = (idx & 15) * 4;
      float4 w = *(const float4*)(W + (size_t)(k0 + kk) * 64 + c4);
      wsm[kk][c4 + 0] = w.x; wsm[kk][c4 + 1] = w.y; wsm[kk][c4 + 2] = w.z; wsm[kk][c4 + 3] = w.w;
    }
    __syncthreads();
#pragma unroll
    for (int k = 0; k < 32; ++k) {
      float4 a = *(const float4*)&xs[k][ty * 4];
      float4 b = *(const float4*)&wsm[k][tx * 4];
      float av[4] = {a.x, a.y, a.z, a.w};
      float bv[4] = {b.x, b.y, b.z, b.w};
#pragma unroll
      for (int i = 0; i < 4; ++i)
#pragma unroll
        for (int j = 0; j < 4; ++j)
          acc[i][j] = fmaf(av[i], bv[j], acc[i][j]);
    }
    __syncthreads();
  }
  // attention weights for this thread's 4 channels (head h = tx>>1, sub-half = tx&1)
  const int h = tx >> 1;
  float as[4], ad[4];
#pragma unroll
  for (int j = 0; j < 4; ++j) {
    as[j] = atts[h * 8 + (tx & 1) * 4 + j];
    ad[j] = attd[h * 8 + (tx & 1) * 4 + j];
  }
#pragma unroll
  for (int i = 0; i < 4; ++i) {
    int r = row0 + ty * 4 + i;
    float ps = 0.f, pd = 0.f;
#pragma unroll
    for (int j = 0; j < 4; ++j) {
      ps = fmaf(acc[i][j], as[j], ps);
      pd = fmaf(acc[i][j], ad[j], pd);
    }
    ps += __shfl_xor(ps, 1);
    pd += __shfl_xor(pd, 1);
    if (r < N) {
      float4 o = make_float4(acc[i][0], acc[i][1], acc[i][2], acc[i][3]);
      *(float4*)(h1 + (size_t)r * 64 + tx * 4) = o;
      if ((tx & 1) == 0) {
        a1s[r * 8 + h] = ps;
        a1d[r * 8 + h] = pd;
      }
    }
  }
}

// -------------------- CSR build --------------------
__global__ __launch_bounds__(256) void init_deg_kernel(int* __restrict__ deg, int N) {
  int i = blockIdx.x * 256 + threadIdx.x;
  if (i < N) deg[i] = 1;  // self-loop
}

__global__ __launch_bounds__(256) void count_kernel(const int* __restrict__ ei, int E, int* __restrict__ deg) {
  int e = blockIdx.x * 256 + threadIdx.x;
  if (e < E) atomicAdd(&deg[ei[E + e]], 1);
}

// exclusive scan, stage 1: per-1024-block scan (in place), block sums out
__global__ __launch_bounds__(256) void scan1_kernel(int* __restrict__ data, int* __restrict__ blocksum, int N) {
  __shared__ int wave_tot[4];
  int t = threadIdx.x;
  int base = blockIdx.x * 1024;
  int v[4];
  int sum = 0;
#pragma unroll
  for (int i = 0; i < 4; ++i) {
    int idx = base + t * 4 + i;
    v[i] = sum;
    int d = (idx < N) ? data[idx] : 0;
    sum += d;
  }
  int lane = t & 63, wv = t >> 6;
  int x = sum;
#pragma unroll
  for (int ofs = 1; ofs < 64; ofs <<= 1) {
    int y = __shfl_up(x, ofs);
    if (lane >= ofs) x += y;
  }
  if (lane == 63) wave_tot[wv] = x;
  __syncthreads();
  int wofs = 0;
  for (int w = 0; w < wv; ++w) wofs += wave_tot[w];
  int excl_thread = wofs + x - sum;
#pragma unroll
  for (int i = 0; i < 4; ++i) {
    int idx = base + t * 4 + i;
    if (idx < N) data[idx] = excl_thread + v[i];
  }
  if (t == 255) blocksum[blockIdx.x] = wofs + x;
}

// stage 2: exclusive scan of block sums (single block; nb <= 256)
__global__ __launch_bounds__(256) void scan2_kernel(int* __restrict__ blocksum, int nb) {
  __shared__ int sm[256];
  int t = threadIdx.x;
  int x = (t < nb) ? blocksum[t] : 0;
  sm[t] = x;
  __syncthreads();
  for (int ofs = 1; ofs < 256; ofs <<= 1) {
    int y = (t >= ofs) ? sm[t - ofs] : 0;
    __syncthreads();
    sm[t] += y;
    __syncthreads();
  }
  if (t < nb) blocksum[t] = sm[t] - x;  // exclusive
}

// stage 3: add block offsets -> rowptr, init cursor
__global__ __launch_bounds__(256) void scan3_kernel(const int* __restrict__ excl, const int* __restrict__ blocksum,
                                                    int* __restrict__ rowptr, int* __restrict__ cursor,
                                                    int N, int ET) {
  int idx = blockIdx.x * 256 + threadIdx.x;
  if (idx < N) {
    int r = excl[idx] + blocksum[idx >> 10];
    rowptr[idx] = r;
    cursor[idx] = r;
  }
  if (idx == N) rowptr[N] = ET;
}

// XCD-class-filtered scatter: class = blockIdx&7 owns dst range [N*c/8, N*(c+1)/8).
// Each class scans the full edge list; writes (esrc + cursor atomics) stay within
// ~1/8 of the output range -> lines accumulate in one XCD's L2 instead of
// bouncing as partial-line HBM writes.
__global__ __launch_bounds__(256) void scatter_kernel(const int* __restrict__ ei, int E, int ET,
                                                      int* __restrict__ cursor, int* __restrict__ esrc, int N) {
  const int cls = blockIdx.x & 7;
  const int nlo = (int)(((long long)N * cls) >> 3);
  const int nhi = (int)(((long long)N * (cls + 1)) >> 3);
  const int chunk = blockIdx.x >> 3;
  const int nchunks = gridDim.x >> 3;
  const long long stride = (long long)nchunks * 256;
  for (long long e = (long long)chunk * 256 + threadIdx.x; e < ET; e += stride) {
    int s, d;
    if (e < E) { d = ei[E + e]; s = ei[e]; }
    else       { d = (int)(e - E); s = d; }
    if (d >= nlo && d < nhi) {
      int pos = atomicAdd(&cursor[d], 1);
      esrc[pos] = s;
    }
  }
}

// -------------------- layer-1 aggregation: wave per dst node, lane = channel --------------------
__global__ __launch_bounds__(256) void agg1_kernel(const int* __restrict__ rowptr, const int* __restrict__ esrc,
                                                   const float* __restrict__ a1s, const float* __restrict__ a1d,
                                                   const float* __restrict__ h1, const float* __restrict__ bias1,
                                                   float* __restrict__ h2, int N) {
  int wid = (blockIdx.x * 256 + threadIdx.x) >> 6;
  int lane = threadIdx.x & 63;
  if (wid >= N) return;
  int n = wid;
  int h = lane >> 3;
  float ad = a1d[n * 8 + h];
  int beg = rowptr[n], end = rowptr[n + 1];
  float acc = 0.f, wsum = 0.f;
  int k = beg;
  for (; k + 1 < end; k += 2) {
    int s0 = esrc[k], s1 = esrc[k + 1];
    float al0 = a1s[s0 * 8 + h] + ad;
    float al1 = a1s[s1 * 8 + h] + ad;
    float g0 = h1[(size_t)s0 * 64 + lane];
    float g1 = h1[(size_t)s1 * 64 + lane];
    al0 = (al0 > 0.f) ? al0 : NEG_SLOPE * al0;
    al1 = (al1 > 0.f) ? al1 : NEG_SLOPE * al1;
    float w0 = __expf(al0), w1 = __expf(al1);
    acc = fmaf(w0, g0, acc);
    acc = fmaf(w1, g1, acc);
    wsum += w0 + w1;
  }
  if (k < end) {
    int s0 = esrc[k];
    float al0 = a1s[s0 * 8 + h] + ad;
    float g0 = h1[(size_t)s0 * 64 + lane];
    al0 = (al0 > 0.f) ? al0 : NEG_SLOPE * al0;
    float w0 = __expf(al0);
    acc = fmaf(w0, g0, acc);
    wsum += w0;
  }
  float v = acc / (wsum + EPSF) + bias1[lane];
  h2[(size_t)n * 64 + lane] = (v > 0.f) ? v : expm1f(v);
}

// -------------------- layer2 projection g = h2 @ W2 + attention scalars --------------------
__global__ __launch_bounds__(256) void l2_proj_kernel(const float* __restrict__ h2, const float* __restrict__ W2,
                                                      const float* __restrict__ atts, const float* __restrict__ attd,
                                                      float* __restrict__ g, float* __restrict__ a2s,
                                                      float* __restrict__ a2d, int N) {
  __shared__ float w[1024];
  int tid = threadIdx.x;
  for (int i = tid; i < 1024; i += 256) w[i] = W2[i];
  __syncthreads();
  int gid = blockIdx.x * 256 + tid;
  int n = gid >> 4, c = gid & 15;
  if (n >= N) return;
  const float* hr = h2 + (size_t)n * 64;
  float acc = 0.f;
#pragma unroll
  for (int k = 0; k < 64; ++k) acc = fmaf(hr[k], w[k * 16 + c], acc);
  g[(size_t)n * 16 + c] = acc;
  float ps = acc * atts[c], pd = acc * attd[c];
#pragma unroll
  for (int m = 1; m < 16; m <<= 1) { ps += __shfl_xor(ps, m); pd += __shfl_xor(pd, m); }
  if (c == 0) { a2s[n] = ps; a2d[n] = pd; }
}

// -------------------- layer-2 aggregation + bias + softmax (fused final) --------------------
__global__ __launch_bounds__(256) void agg2_kernel(const int* __restrict__ rowptr, const int* __restrict__ esrc,
                                                   const float* __restrict__ a2s, const float* __restrict__ a2d,
                                                   const float* __restrict__ g, const float* __restrict__ bias2,
                                                   float* __restrict__ out_sm, float* __restrict__ emb, int N) {
  int wid = (blockIdx.x * 256 + threadIdx.x) >> 6;
  int lane = threadIdx.x & 63;
  if (wid >= N) return;
  int n = wid;
  int c = lane & 15, sub = lane >> 4;
  float ad = a2d[n];
  int beg = rowptr[n], end = rowptr[n + 1];
  float acc = 0.f, wsum = 0.f;
  for (int k = beg + sub; k < end; k += 4) {
    int s = esrc[k];
    float al = a2s[s] + ad;
    al = (al > 0.f) ? al : NEG_SLOPE * al;
    float w = __expf(al);
    acc = fmaf(w, g[(size_t)s * 16 + c], acc);
    wsum += w;
  }
  acc += __shfl_xor(acc, 16); acc += __shfl_xor(acc, 32);
  wsum += __shfl_xor(wsum, 16); wsum += __shfl_xor(wsum, 32);
  float v = acc / (wsum + EPSF) + bias2[c];
  float m = v;
#pragma unroll
  for (int k2 = 1; k2 < 16; k2 <<= 1) m = fmaxf(m, __shfl_xor(m, k2));
  float e = __expf(v - m);
  float ssum = e;
#pragma unroll
  for (int k2 = 1; k2 < 16; k2 <<= 1) ssum += __shfl_xor(ssum, k2);
  if (sub == 0) {
    emb[(size_t)n * 16 + c] = v;
    out_sm[(size_t)n * 16 + c] = e / ssum;
  }
}

extern "C" void kernel_launch(void* const* d_in, const int* in_sizes, int n_in,
                              void* d_out, int out_size, void* d_ws, size_t ws_size,
                              hipStream_t stream) {
  const float* x     = (const float*)d_in[0];
  const int*   ei    = (const int*)d_in[1];
  const float* W1    = (const float*)d_in[2];
  const float* atts1 = (const float*)d_in[3];
  const float* attd1 = (const float*)d_in[4];
  const float* bias1 = (const float*)d_in[5];
  const float* W2    = (const float*)d_in[6];
  const float* atts2 = (const float*)d_in[7];
  const float* attd2 = (const float*)d_in[8];
  const float* bias2 = (const float*)d_in[9];

  const int N = in_sizes[0] / 512;
  const int E = in_sizes[1] / 2;
  const int ET = E + N;

  // workspace layout (4-byte elems). g/a2s/a2d alias the h1 region (dead by then).
  float* ws   = (float*)d_ws;
  float* h1   = ws;                       // N*64  (later reused: g N*16, a2s N, a2d N)
  float* a1s  = h1  + (size_t)N * 64;     // N*8
  float* a1d  = a1s + (size_t)N * 8;      // N*8
  float* h2   = a1d + (size_t)N * 8;      // N*64
  int*   deg  = (int*)(h2 + (size_t)N * 64); // N (in-place becomes excl-scan)
  int*   rowptr = deg + N;                // N+1
  int*   cursor = rowptr + N + 1;         // N
  int*   blocksum = cursor + N;           // 256
  int*   esrc = blocksum + 256;           // ET

  float* g   = h1;                        // N*16 (aliases h1)
  float* a2s = h1 + (size_t)N * 16;       // N
  float* a2d = a2s + N;                   // N

  float* out_sm = (float*)d_out;            // softmax output [N,16]
  float* emb    = out_sm + (size_t)N * 16;  // node_embeddings [N,16]

  const int nb = (N + 1023) / 1024;  // scan blocks (<=256 for N<=262144)

  // CSR build
  init_deg_kernel<<<(N + 255) / 256, 256, 0, stream>>>(deg, N);
  count_kernel<<<(E + 255) / 256, 256, 0, stream>>>(ei, E, deg);
  scan1_kernel<<<nb, 256, 0, stream>>>(deg, blocksum, N);
  scan2_kernel<<<1, 256, 0, stream>>>(blocksum, nb);
  scan3_kernel<<<(N + 256) / 256, 256, 0, stream>>>(deg, blocksum, rowptr, cursor, N, ET);
  scatter_kernel<<<8 * 1024, 256, 0, stream>>>(ei, E, ET, cursor, esrc, N);

  // layer 1 (att1 fused into gemm1 epilogue)
  gemm1_kernel<<<(N + 63) / 64, 256, 0, stream>>>(x, W1, atts1, attd1, h1, a1s, a1d, N);
  agg1_kernel<<<(N + 3) / 4, 256, 0, stream>>>(rowptr, esrc, a1s, a1d, h1, bias1, h2, N);

  // layer 2
  l2_proj_kernel<<<(N * 16 + 255) / 256, 256, 0, stream>>>(h2, W2, atts2, attd2, g, a2s, a2d, N);
  agg2_kernel<<<(N + 3) / 4, 256, 0, stream>>>(rowptr, esrc, a2s, a2d, g, bias2, out_sm, emb, N);
}